// Round 1
// baseline (2973.728 us; speedup 1.0000x reference)
//
#include <hip/hip_runtime.h>

// GCN: 2x (GCNConv + ReLU) + FC.  N=100000, E=1600000, F: 128 -> 64 -> 64 -> 32.
// All fp32.  Self-loops folded into the finalize kernel (agg + h[i]*dinv[i]^2 + b).

#define THREADS 256

__global__ __launch_bounds__(THREADS) void deg_kernel(const int* __restrict__ dst, int E,
                                                      float* __restrict__ deg) {
    int e = blockIdx.x * blockDim.x + threadIdx.x;
    if (e < E) atomicAdd(&deg[dst[e]], 1.0f);
}

__global__ __launch_bounds__(THREADS) void dinv_kernel(float* __restrict__ dinv, int N) {
    int i = blockIdx.x * blockDim.x + threadIdx.x;
    if (i < N) dinv[i] = rsqrtf(dinv[i] + 1.0f);   // +1 for the self-loop
}

__global__ __launch_bounds__(THREADS) void norm_kernel(const int* __restrict__ src,
                                                       const int* __restrict__ dst,
                                                       const float* __restrict__ dinv,
                                                       float* __restrict__ norm, int E) {
    int e = blockIdx.x * blockDim.x + threadIdx.x;
    if (e < E) norm[e] = dinv[src[e]] * dinv[dst[e]];
}

// Y[N,M] = X[N,K] @ W[K,M] (+ bias).  W staged in LDS; ROWS=256/M nodes per block.
template <int K, int M, bool BIAS>
__global__ __launch_bounds__(THREADS) void matmul_kernel(const float* __restrict__ X,
                                                         const float* __restrict__ W,
                                                         const float* __restrict__ bias,
                                                         float* __restrict__ Y, int N) {
    constexpr int ROWS = THREADS / M;
    __shared__ float Ws[K * M];
    __shared__ float Xs[ROWS * K];
    const int t = threadIdx.x;
    // Stage W (K*M floats), coalesced, vectorized.
    const float4* Wg = (const float4*)W;
    float4* Wl = (float4*)Ws;
    for (int i = t; i < K * M / 4; i += THREADS) Wl[i] = Wg[i];
    // Stage ROWS rows of X (contiguous block of ROWS*K floats).
    const int row0 = blockIdx.x * ROWS;
    if (row0 + ROWS <= N) {
        const float4* Xg = (const float4*)(X + (size_t)row0 * K);
        float4* Xl = (float4*)Xs;
        for (int i = t; i < ROWS * K / 4; i += THREADS) Xl[i] = Xg[i];
    } else {
        for (int i = t; i < ROWS * K; i += THREADS) {
            int node = row0 + i / K;
            Xs[i] = (node < N) ? X[(size_t)node * K + (i % K)] : 0.0f;
        }
    }
    __syncthreads();
    const int r = t / M, c = t % M;
    const int node = row0 + r;
    if (node < N) {
        float acc = BIAS ? bias[c] : 0.0f;
#pragma unroll
        for (int k = 0; k < K; ++k) acc = fmaf(Xs[r * K + k], Ws[k * M + c], acc);
        Y[(size_t)node * M + c] = acc;
    }
}

// out[dst] += H[src] * norm.  F=64: 16 threads/edge, float4 gather + 4 atomics each.
__global__ __launch_bounds__(THREADS) void agg_kernel(const int* __restrict__ src,
                                                      const int* __restrict__ dst,
                                                      const float* __restrict__ norm,
                                                      const float* __restrict__ H,
                                                      float* __restrict__ out, int E) {
    int idx = blockIdx.x * blockDim.x + threadIdx.x;
    int e = idx >> 4;        // / 16 chunks
    int ch = idx & 15;       // which float4 of the 64-wide feature row
    if (e >= E) return;
    const int s = src[e];
    const int d = dst[e];
    const float nrm = norm[e];
    const float4 v = *(const float4*)(H + (size_t)s * 64 + ch * 4);
    float* o = out + (size_t)d * 64 + ch * 4;
    atomicAdd(o + 0, v.x * nrm);
    atomicAdd(o + 1, v.y * nrm);
    atomicAdd(o + 2, v.z * nrm);
    atomicAdd(o + 3, v.w * nrm);
}

// agg[i,f] = relu(agg[i,f] + H[i,f]*dinv[i]^2 + b[f])   (self-loop + bias + relu), F=64
__global__ __launch_bounds__(THREADS) void finalize_kernel(float* __restrict__ agg,
                                                           const float* __restrict__ H,
                                                           const float* __restrict__ dinv,
                                                           const float* __restrict__ bias,
                                                           int N) {
    int idx = blockIdx.x * blockDim.x + threadIdx.x;
    if (idx < N * 64) {
        int i = idx >> 6, f = idx & 63;
        float di = dinv[i];
        float v = fmaf(H[idx], di * di, agg[idx]) + bias[f];
        agg[idx] = fmaxf(v, 0.0f);
    }
}

extern "C" void kernel_launch(void* const* d_in, const int* in_sizes, int n_in,
                              void* d_out, int out_size, void* d_ws, size_t ws_size,
                              hipStream_t stream) {
    const float* x   = (const float*)d_in[0];
    const int*   ei  = (const int*)d_in[1];   // [2, E] int32
    const float* W1  = (const float*)d_in[3];
    const float* b1  = (const float*)d_in[4];
    const float* W2  = (const float*)d_in[5];
    const float* b2  = (const float*)d_in[6];
    const float* Wfc = (const float*)d_in[7];
    const float* bfc = (const float*)d_in[8];
    float* out = (float*)d_out;

    const int N = in_sizes[0] / 128;
    const int E = in_sizes[1] / 2;
    const int* src = ei;
    const int* dst = ei + E;

    // Workspace layout (floats): dinv[N] | norm[E] | bufA[N*64] | bufB[N*64]
    float* dinv = (float*)d_ws;
    float* norm = dinv + N;
    float* bufA = norm + E;
    float* bufB = bufA + (size_t)N * 64;

    const int gE  = (E + THREADS - 1) / THREADS;
    const int gN  = (N + THREADS - 1) / THREADS;
    const int gNF = ((N * 64) + THREADS - 1) / THREADS;
    const int gAgg = (int)(((size_t)E * 16 + THREADS - 1) / THREADS);

    // Degree -> dinv -> per-edge norm (shared by both conv layers).
    hipMemsetAsync(dinv, 0, (size_t)N * sizeof(float), stream);
    deg_kernel<<<gE, THREADS, 0, stream>>>(dst, E, dinv);
    dinv_kernel<<<gN, THREADS, 0, stream>>>(dinv, N);
    norm_kernel<<<gE, THREADS, 0, stream>>>(src, dst, dinv, norm, E);

    // Layer 1: h1 = x @ W1 (128->64); aggregate; relu(+b1, self-loop).
    matmul_kernel<128, 64, false><<<(N + 3) / 4, THREADS, 0, stream>>>(x, W1, nullptr, bufA, N);
    hipMemsetAsync(bufB, 0, (size_t)N * 64 * sizeof(float), stream);
    agg_kernel<<<gAgg, THREADS, 0, stream>>>(src, dst, norm, bufA, bufB, E);
    finalize_kernel<<<gNF, THREADS, 0, stream>>>(bufB, bufA, dinv, b1, N);

    // Layer 2: h2 = relu1 @ W2 (64->64); aggregate; relu(+b2, self-loop).
    matmul_kernel<64, 64, false><<<(N + 3) / 4, THREADS, 0, stream>>>(bufB, W2, nullptr, bufA, N);
    hipMemsetAsync(bufB, 0, (size_t)N * 64 * sizeof(float), stream);
    agg_kernel<<<gAgg, THREADS, 0, stream>>>(src, dst, norm, bufA, bufB, E);
    finalize_kernel<<<gNF, THREADS, 0, stream>>>(bufB, bufA, dinv, b2, N);

    // FC: out = relu2 @ Wfc + bfc (64->32).
    matmul_kernel<64, 32, true><<<(N + 7) / 8, THREADS, 0, stream>>>(bufB, Wfc, bfc, out, N);
}

// Round 2
// 666.809 us; speedup vs baseline: 4.4596x; 4.4596x over previous
//
#include <hip/hip_runtime.h>

// GCN: 2x (GCNConv + ReLU) + FC.  N=100000, E=1600000, F: 128 -> 64 -> 64 -> 32. fp32.
//
// R2: atomic scatter (1.6 GB HBM write-through per layer, R1 rocprof) replaced by
// dst-sorted CSR (counting sort per call) + one-wave-per-node register aggregation.
// norm[e]=dinv[s]*dinv[d] factored: matmul epilogue scales rows by dinv (Hs = h*dinv),
// agg does out[i] = relu(dinv[i]*(Hs[i] + sum Hs[src]) + b). No atomics in agg, no
// norm array, no finalize pass, no 25.6MB zero-memsets.

#define THREADS 256
#define SCAN_BLOCK 1024

// ---- CSR build -------------------------------------------------------------

__global__ __launch_bounds__(THREADS) void count_kernel(const int* __restrict__ dst, int E,
                                                        int* __restrict__ cnt) {
    int e = blockIdx.x * blockDim.x + threadIdx.x;
    if (e < E) atomicAdd(&cnt[dst[e]], 1);
}

__global__ __launch_bounds__(THREADS) void dinv_kernel(const int* __restrict__ cnt,
                                                       float* __restrict__ dinv, int N) {
    int i = blockIdx.x * blockDim.x + threadIdx.x;
    if (i < N) dinv[i] = rsqrtf((float)cnt[i] + 1.0f);  // +1 self-loop
}

// In-place exclusive scan of row[] (Hillis-Steele per block) + per-block totals.
__global__ __launch_bounds__(SCAN_BLOCK) void scan1_kernel(int* __restrict__ row,
                                                           int* __restrict__ bsum, int N) {
    __shared__ int s[SCAN_BLOCK];
    const int t = threadIdx.x;
    const int gid = blockIdx.x * SCAN_BLOCK + t;
    const int v = (gid < N) ? row[gid] : 0;
    s[t] = v;
    __syncthreads();
    for (int off = 1; off < SCAN_BLOCK; off <<= 1) {
        int u = (t >= off) ? s[t - off] : 0;
        __syncthreads();
        s[t] += u;
        __syncthreads();
    }
    if (gid < N) row[gid] = s[t] - v;  // exclusive
    if (t == SCAN_BLOCK - 1) bsum[blockIdx.x] = s[t];
}

__global__ void scan2_kernel(int* __restrict__ bsum, int nb) {
    if (blockIdx.x == 0 && threadIdx.x == 0) {
        int run = 0;
        for (int b = 0; b < nb; ++b) { int t = bsum[b]; bsum[b] = run; run += t; }
    }
}

__global__ __launch_bounds__(SCAN_BLOCK) void scan3_kernel(int* __restrict__ row,
                                                           const int* __restrict__ bsum, int N) {
    int gid = blockIdx.x * SCAN_BLOCK + threadIdx.x;
    if (gid < N) row[gid] += bsum[blockIdx.x];
}

// Bucket-scatter src ids by dst. Bumps row[] from row_start to row_end;
// agg reads segment i as [row[i-1], row[i]] (row[-1] := 0).
__global__ __launch_bounds__(THREADS) void scatter_kernel(const int* __restrict__ src,
                                                          const int* __restrict__ dst, int E,
                                                          int* __restrict__ row,
                                                          int* __restrict__ src_sorted) {
    int e = blockIdx.x * blockDim.x + threadIdx.x;
    if (e < E) {
        int pos = atomicAdd(&row[dst[e]], 1);
        src_sorted[pos] = src[e];
    }
}

// ---- Dense matmul: Y[N,M] = (X[N,K] @ W[K,M]) [*dinv[row]] [+bias] ---------

template <int K, int M, bool BIAS, bool SCALE>
__global__ __launch_bounds__(THREADS) void matmul_kernel(const float* __restrict__ X,
                                                         const float* __restrict__ W,
                                                         const float* __restrict__ bias,
                                                         const float* __restrict__ dinv,
                                                         float* __restrict__ Y, int N) {
    constexpr int ROWS = THREADS / M;
    __shared__ float Ws[K * M];
    __shared__ float Xs[ROWS * K];
    const int t = threadIdx.x;
    const float4* Wg = (const float4*)W;
    float4* Wl = (float4*)Ws;
    for (int i = t; i < K * M / 4; i += THREADS) Wl[i] = Wg[i];
    const int row0 = blockIdx.x * ROWS;
    if (row0 + ROWS <= N) {
        const float4* Xg = (const float4*)(X + (size_t)row0 * K);
        float4* Xl = (float4*)Xs;
        for (int i = t; i < ROWS * K / 4; i += THREADS) Xl[i] = Xg[i];
    } else {
        for (int i = t; i < ROWS * K; i += THREADS) {
            int node = row0 + i / K;
            Xs[i] = (node < N) ? X[(size_t)node * K + (i % K)] : 0.0f;
        }
    }
    __syncthreads();
    const int r = t / M, c = t % M;
    const int node = row0 + r;
    if (node < N) {
        float acc = 0.0f;
#pragma unroll
        for (int k = 0; k < K; ++k) acc = fmaf(Xs[r * K + k], Ws[k * M + c], acc);
        if (SCALE) acc *= dinv[node];
        if (BIAS) acc += bias[c];
        Y[(size_t)node * M + c] = acc;
    }
}

// ---- Aggregation: one wave per node, lane = feature (F=64) -----------------
// out[i,f] = relu(dinv[i] * (Hs[i,f] + sum_{s in N(i)} Hs[s,f]) + b[f])

__global__ __launch_bounds__(THREADS) void agg_kernel(const int* __restrict__ row,
                                                      const int* __restrict__ src_sorted,
                                                      const float* __restrict__ dinv,
                                                      const float* __restrict__ Hs,
                                                      const float* __restrict__ bias,
                                                      float* __restrict__ out, int N) {
    const int idx = blockIdx.x * blockDim.x + threadIdx.x;
    const int node = idx >> 6;
    const int lane = idx & 63;
    if (node >= N) return;
    const int start = (node == 0) ? 0 : row[node - 1];
    const int end = row[node];
    float acc = Hs[(size_t)node * 64 + lane];  // self-loop term
    int j = start;
    int s_next = (j < end) ? src_sorted[j] : 0;
    for (; j < end; ++j) {
        const int s = s_next;
        if (j + 1 < end) s_next = src_sorted[j + 1];
        acc += Hs[(size_t)s * 64 + lane];
    }
    float v = fmaf(acc, dinv[node], bias[lane]);
    out[(size_t)node * 64 + lane] = fmaxf(v, 0.0f);
}

// ---- Launch ----------------------------------------------------------------

extern "C" void kernel_launch(void* const* d_in, const int* in_sizes, int n_in,
                              void* d_out, int out_size, void* d_ws, size_t ws_size,
                              hipStream_t stream) {
    const float* x   = (const float*)d_in[0];
    const int*   ei  = (const int*)d_in[1];   // [2, E] int32
    const float* W1  = (const float*)d_in[3];
    const float* b1  = (const float*)d_in[4];
    const float* W2  = (const float*)d_in[5];
    const float* b2  = (const float*)d_in[6];
    const float* Wfc = (const float*)d_in[7];
    const float* bfc = (const float*)d_in[8];
    float* out = (float*)d_out;

    const int N = in_sizes[0] / 128;
    const int E = in_sizes[1] / 2;
    const int* src = ei;
    const int* dst = ei + E;

    // ws layout: row[N] (cnt -> row_start -> row_end) | dinv[N] | src_sorted[E]
    //            | bufA[N*64] | bufB[N*64] | bsum[nb]       (~58 MB)
    int*   row  = (int*)d_ws;
    float* dinv = (float*)(row + N);
    int*   ssrc = (int*)(dinv + N);
    float* bufA = (float*)(ssrc + E);
    float* bufB = bufA + (size_t)N * 64;
    int*   bsum = (int*)(bufB + (size_t)N * 64);

    const int nb  = (N + SCAN_BLOCK - 1) / SCAN_BLOCK;
    const int gE  = (E + THREADS - 1) / THREADS;
    const int gN  = (N + THREADS - 1) / THREADS;
    const int gW  = ((N * 64) + THREADS - 1) / THREADS;  // one wave per node

    // CSR build (shared by both conv layers).
    hipMemsetAsync(row, 0, (size_t)N * sizeof(int), stream);
    count_kernel<<<gE, THREADS, 0, stream>>>(dst, E, row);
    dinv_kernel<<<gN, THREADS, 0, stream>>>(row, dinv, N);
    scan1_kernel<<<nb, SCAN_BLOCK, 0, stream>>>(row, bsum, N);
    scan2_kernel<<<1, 64, 0, stream>>>(bsum, nb);
    scan3_kernel<<<nb, SCAN_BLOCK, 0, stream>>>(row, bsum, N);
    scatter_kernel<<<gE, THREADS, 0, stream>>>(src, dst, E, row, ssrc);

    // Layer 1: Hs1 = (x @ W1)*dinv ; out = relu(dinv*(Hs1[i] + gather-sum) + b1)
    matmul_kernel<128, 64, false, true><<<(N + 3) / 4, THREADS, 0, stream>>>(x, W1, nullptr, dinv, bufA, N);
    agg_kernel<<<gW, THREADS, 0, stream>>>(row, ssrc, dinv, bufA, b1, bufB, N);

    // Layer 2
    matmul_kernel<64, 64, false, true><<<(N + 3) / 4, THREADS, 0, stream>>>(bufB, W2, nullptr, dinv, bufA, N);
    agg_kernel<<<gW, THREADS, 0, stream>>>(row, ssrc, dinv, bufA, b2, bufB, N);

    // FC
    matmul_kernel<64, 32, true, false><<<(N + 7) / 8, THREADS, 0, stream>>>(bufB, Wfc, bfc, nullptr, out, N);
}

// Round 3
// 561.635 us; speedup vs baseline: 5.2948x; 1.1873x over previous
//
#include <hip/hip_runtime.h>

// GCN: 2x (GCNConv + ReLU) + FC.  N=100000, E=1600000, F: 128 -> 64 -> 64 -> 32. fp32.
//
// R3: matmuls were LDS-BW bound (8 B/fma at 1 output/thread). Now 4x4 register
// blocking: float4 LDS reads, 2 B/fma -> VALU-bound. CSR build + wave-per-node
// gather agg unchanged from R2 (scatter_kernel is the known 128 us floor, R4 target).

#define THREADS 256
#define SCAN_BLOCK 1024

// ---- CSR build -------------------------------------------------------------

__global__ __launch_bounds__(THREADS) void count_kernel(const int* __restrict__ dst, int E,
                                                        int* __restrict__ cnt) {
    int e = blockIdx.x * blockDim.x + threadIdx.x;
    if (e < E) atomicAdd(&cnt[dst[e]], 1);
}

// Exclusive scan of row[] (Hillis-Steele per block) + per-block totals.
// Fused: dinv[i] = rsqrt(cnt[i]+1) computed from the pre-scan value.
__global__ __launch_bounds__(SCAN_BLOCK) void scan1_kernel(int* __restrict__ row,
                                                           int* __restrict__ bsum,
                                                           float* __restrict__ dinv, int N) {
    __shared__ int s[SCAN_BLOCK];
    const int t = threadIdx.x;
    const int gid = blockIdx.x * SCAN_BLOCK + t;
    const int v = (gid < N) ? row[gid] : 0;
    if (gid < N) dinv[gid] = rsqrtf((float)v + 1.0f);  // +1 self-loop
    s[t] = v;
    __syncthreads();
    for (int off = 1; off < SCAN_BLOCK; off <<= 1) {
        int u = (t >= off) ? s[t - off] : 0;
        __syncthreads();
        s[t] += u;
        __syncthreads();
    }
    if (gid < N) row[gid] = s[t] - v;  // exclusive
    if (t == SCAN_BLOCK - 1) bsum[blockIdx.x] = s[t];
}

__global__ void scan2_kernel(int* __restrict__ bsum, int nb) {
    if (blockIdx.x == 0 && threadIdx.x == 0) {
        int run = 0;
        for (int b = 0; b < nb; ++b) { int t = bsum[b]; bsum[b] = run; run += t; }
    }
}

__global__ __launch_bounds__(SCAN_BLOCK) void scan3_kernel(int* __restrict__ row,
                                                           const int* __restrict__ bsum, int N) {
    int gid = blockIdx.x * SCAN_BLOCK + threadIdx.x;
    if (gid < N) row[gid] += bsum[blockIdx.x];
}

// Bucket-scatter src ids by dst. Bumps row[] start->end; agg reads segment i as
// [row[i-1], row[i]] (row[-1] := 0).
__global__ __launch_bounds__(THREADS) void scatter_kernel(const int* __restrict__ src,
                                                          const int* __restrict__ dst, int E,
                                                          int* __restrict__ row,
                                                          int* __restrict__ src_sorted) {
    int e = blockIdx.x * blockDim.x + threadIdx.x;
    if (e < E) {
        int pos = atomicAdd(&row[dst[e]], 1);
        src_sorted[pos] = src[e];
    }
}

// ---- Dense matmul: Y[N,M] = (X[N,K] @ W[K,M]) [*dinv[row]] [+bias] ---------
// Tile TILE_R rows x M cols; each thread 4 rows x 4 cols (needs TILE_R/4*M/4==256).
// Per 4-k step: 8 float4 LDS reads feed 64 fma -> 2 B/fma, VALU-bound.
// KP pads the Xs row stride (+4 floats, keeps 16B align) to break the row-bank
// alias down to free 2-way — skipped for K=128 where LDS would exceed 64 KB.

template <int K, int M, int TILE_R, bool BIAS, bool SCALE>
__global__ __launch_bounds__(THREADS) void mm_kernel(const float* __restrict__ X,
                                                     const float* __restrict__ W,
                                                     const float* __restrict__ bias,
                                                     const float* __restrict__ dinv,
                                                     float* __restrict__ Y, int N) {
    static_assert((TILE_R / 4) * (M / 4) == THREADS, "tile/thread mismatch");
    constexpr int KP = (K == 128) ? K : K + 4;  // Xs row stride in floats
    constexpr int KQ = K / 4;
    __shared__ float Xs[TILE_R * KP];
    __shared__ float Ws[K * M];
    const int t = threadIdx.x;
    const int row0 = blockIdx.x * TILE_R;

    for (int i = t; i < K * M / 4; i += THREADS)
        ((float4*)Ws)[i] = ((const float4*)W)[i];

    const bool full = (row0 + TILE_R <= N);
    for (int i = t; i < TILE_R * KQ; i += THREADS) {
        const int r = i / KQ, kq = i % KQ;
        float4 v = {0.f, 0.f, 0.f, 0.f};
        if (full || row0 + r < N)
            v = *(const float4*)(X + (size_t)(row0 + r) * K + kq * 4);
        *(float4*)&Xs[r * KP + kq * 4] = v;
    }
    __syncthreads();

    constexpr int CG = M / 4;
    const int rg = t / CG;  // rows rg*4 .. rg*4+3
    const int cg = t % CG;  // cols cg*4 .. cg*4+3
    float acc[4][4] = {};
    const float* xb = &Xs[(rg * 4) * KP];
    const float* wb = &Ws[cg * 4];

#define GCN_STEP(XV, WV)                                                                  \
    acc[0][0] = fmaf(xv0.XV, WV.x, acc[0][0]); acc[0][1] = fmaf(xv0.XV, WV.y, acc[0][1]); \
    acc[0][2] = fmaf(xv0.XV, WV.z, acc[0][2]); acc[0][3] = fmaf(xv0.XV, WV.w, acc[0][3]); \
    acc[1][0] = fmaf(xv1.XV, WV.x, acc[1][0]); acc[1][1] = fmaf(xv1.XV, WV.y, acc[1][1]); \
    acc[1][2] = fmaf(xv1.XV, WV.z, acc[1][2]); acc[1][3] = fmaf(xv1.XV, WV.w, acc[1][3]); \
    acc[2][0] = fmaf(xv2.XV, WV.x, acc[2][0]); acc[2][1] = fmaf(xv2.XV, WV.y, acc[2][1]); \
    acc[2][2] = fmaf(xv2.XV, WV.z, acc[2][2]); acc[2][3] = fmaf(xv2.XV, WV.w, acc[2][3]); \
    acc[3][0] = fmaf(xv3.XV, WV.x, acc[3][0]); acc[3][1] = fmaf(xv3.XV, WV.y, acc[3][1]); \
    acc[3][2] = fmaf(xv3.XV, WV.z, acc[3][2]); acc[3][3] = fmaf(xv3.XV, WV.w, acc[3][3]);

    for (int k = 0; k < K; k += 4) {
        const float4 xv0 = *(const float4*)(xb + 0 * KP + k);
        const float4 xv1 = *(const float4*)(xb + 1 * KP + k);
        const float4 xv2 = *(const float4*)(xb + 2 * KP + k);
        const float4 xv3 = *(const float4*)(xb + 3 * KP + k);
        const float4 wv0 = *(const float4*)(wb + (size_t)(k + 0) * M);
        const float4 wv1 = *(const float4*)(wb + (size_t)(k + 1) * M);
        const float4 wv2 = *(const float4*)(wb + (size_t)(k + 2) * M);
        const float4 wv3 = *(const float4*)(wb + (size_t)(k + 3) * M);
        GCN_STEP(x, wv0)
        GCN_STEP(y, wv1)
        GCN_STEP(z, wv2)
        GCN_STEP(w, wv3)
    }
#undef GCN_STEP

#pragma unroll
    for (int i = 0; i < 4; ++i) {
        const int row = row0 + rg * 4 + i;
        if (row < N) {
            float4 o = {acc[i][0], acc[i][1], acc[i][2], acc[i][3]};
            if (SCALE) {
                const float d = dinv[row];
                o.x *= d; o.y *= d; o.z *= d; o.w *= d;
            }
            if (BIAS) {
                o.x += bias[cg * 4 + 0]; o.y += bias[cg * 4 + 1];
                o.z += bias[cg * 4 + 2]; o.w += bias[cg * 4 + 3];
            }
            *(float4*)(Y + (size_t)row * M + cg * 4) = o;
        }
    }
}

// ---- Aggregation: one wave per node, lane = feature (F=64) -----------------
// out[i,f] = relu(dinv[i] * (Hs[i,f] + sum_{s in N(i)} Hs[s,f]) + b[f])

__global__ __launch_bounds__(THREADS) void agg_kernel(const int* __restrict__ row,
                                                      const int* __restrict__ src_sorted,
                                                      const float* __restrict__ dinv,
                                                      const float* __restrict__ Hs,
                                                      const float* __restrict__ bias,
                                                      float* __restrict__ out, int N) {
    const int idx = blockIdx.x * blockDim.x + threadIdx.x;
    const int node = idx >> 6;
    const int lane = idx & 63;
    if (node >= N) return;
    const int start = (node == 0) ? 0 : row[node - 1];
    const int end = row[node];
    float acc = Hs[(size_t)node * 64 + lane];  // self-loop term
    int j = start;
    for (; j + 1 < end; j += 2) {
        const int s0 = src_sorted[j];
        const int s1 = src_sorted[j + 1];
        const float a0 = Hs[(size_t)s0 * 64 + lane];
        const float a1 = Hs[(size_t)s1 * 64 + lane];
        acc += a0;
        acc += a1;
    }
    if (j < end) acc += Hs[(size_t)src_sorted[j] * 64 + lane];
    const float v = fmaf(acc, dinv[node], bias[lane]);
    out[(size_t)node * 64 + lane] = fmaxf(v, 0.0f);
}

// ---- Launch ----------------------------------------------------------------

extern "C" void kernel_launch(void* const* d_in, const int* in_sizes, int n_in,
                              void* d_out, int out_size, void* d_ws, size_t ws_size,
                              hipStream_t stream) {
    const float* x   = (const float*)d_in[0];
    const int*   ei  = (const int*)d_in[1];   // [2, E] int32
    const float* W1  = (const float*)d_in[3];
    const float* b1  = (const float*)d_in[4];
    const float* W2  = (const float*)d_in[5];
    const float* b2  = (const float*)d_in[6];
    const float* Wfc = (const float*)d_in[7];
    const float* bfc = (const float*)d_in[8];
    float* out = (float*)d_out;

    const int N = in_sizes[0] / 128;
    const int E = in_sizes[1] / 2;
    const int* src = ei;
    const int* dst = ei + E;

    // ws layout: row[N] | dinv[N] | src_sorted[E] | bufA[N*64] | bufB[N*64] | bsum[nb]
    int*   row  = (int*)d_ws;
    float* dinv = (float*)(row + N);
    int*   ssrc = (int*)(dinv + N);
    float* bufA = (float*)(ssrc + E);
    float* bufB = bufA + (size_t)N * 64;
    int*   bsum = (int*)(bufB + (size_t)N * 64);

    const int nb = (N + SCAN_BLOCK - 1) / SCAN_BLOCK;
    const int gE = (E + THREADS - 1) / THREADS;
    const int gW = ((N * 64) + THREADS - 1) / THREADS;  // one wave per node

    // CSR build (shared by both conv layers).
    hipMemsetAsync(row, 0, (size_t)N * sizeof(int), stream);
    count_kernel<<<gE, THREADS, 0, stream>>>(dst, E, row);
    scan1_kernel<<<nb, SCAN_BLOCK, 0, stream>>>(row, bsum, dinv, N);
    scan2_kernel<<<1, 64, 0, stream>>>(bsum, nb);
    scan3_kernel<<<nb, SCAN_BLOCK, 0, stream>>>(row, bsum, N);
    scatter_kernel<<<gE, THREADS, 0, stream>>>(src, dst, E, row, ssrc);

    // Layer 1: Hs1 = (x @ W1)*dinv ; out = relu(dinv*(Hs1[i] + gather-sum) + b1)
    mm_kernel<128, 64, 64, false, true><<<(N + 63) / 64, THREADS, 0, stream>>>(x, W1, nullptr, dinv, bufA, N);
    agg_kernel<<<gW, THREADS, 0, stream>>>(row, ssrc, dinv, bufA, b1, bufB, N);

    // Layer 2
    mm_kernel<64, 64, 64, false, true><<<(N + 63) / 64, THREADS, 0, stream>>>(bufB, W2, nullptr, dinv, bufA, N);
    agg_kernel<<<gW, THREADS, 0, stream>>>(row, ssrc, dinv, bufA, b2, bufB, N);

    // FC
    mm_kernel<64, 32, 128, true, false><<<(N + 127) / 128, THREADS, 0, stream>>>(bufB, Wfc, bfc, nullptr, out, N);
}